// Round 8
// baseline (109.747 us; speedup 1.0000x reference)
//
#include <hip/hip_runtime.h>
#include <hip/hip_bf16.h>

#define BATCH  16384
#define FDIM   256
#define EDIM   128
#define KN     32
#define NNODES 100000

typedef __bf16 bf16x8 __attribute__((ext_vector_type(8)));
typedef float  f32x4  __attribute__((ext_vector_type(4)));

__device__ __forceinline__ unsigned short f2bf(float x) {
    return __builtin_bit_cast(unsigned short, (__bf16)x);
}
__device__ __forceinline__ float bflo(unsigned v) {
    return __builtin_bit_cast(float, v << 16);
}
__device__ __forceinline__ float bfhi(unsigned v) {
    return __builtin_bit_cast(float, v & 0xffff0000u);
}

// ---------- ws layout ----------
// S[NNODES][128] bf16, P[NNODES][128] bf16
// wbt: combined B^T bf16, plain row-major [j=256][k=256]
//      (j = output col; j<128 -> S head, else P head)
#define SP_BYTES  ((size_t)NNODES * 256)
#define WBT_BYTES ((size_t)256 * 256 * 2)
#define NEW_WS    (2 * SP_BYTES + WBT_BYTES)

// ---------------- kernel: W[512][128] f32 -> wbt[j][k] bf16 ----------------
// Wc[k][j] = (j<128) ? W[k][j] : W[k+256][j-128],  k,j in [0,256)
__global__ void conv_w3(const float* __restrict__ weight, char* __restrict__ wbt)
{
    const int gid = blockIdx.x * 256 + threadIdx.x;   // 8192 threads
    const int j   = gid >> 5;          // 0..255
    const int g   = gid & 31;          // k-granule of 8
    union { unsigned short u[8]; uint4 v; } p;
    #pragma unroll
    for (int e = 0; e < 8; ++e) {
        const int k = g * 8 + e;
        const float w = (j < 128) ? weight[(size_t)k * EDIM + j]
                                  : weight[(size_t)(k + 256) * EDIM + (j - 128)];
        p.u[e] = f2bf(w);
    }
    *(uint4*)(wbt + (size_t)j * 512 + g * 16) = p.v;
}

// ---------------- kernel: proj6  S|P = F @ Wc ----------------
// Pure cache-fed streaming MFMA: no LDS, no barriers, no staging.
// 256 thr / 4 waves; block = 64 rows x 256 cols; wave = 64 rows x 64 cols.
// Per kt (BK=32): 4 B-loads from L2-resident wbt, 8 A-loads from feat, 16 MFMA.
__global__ __launch_bounds__(256, 3)
void proj6(const float* __restrict__ feat, const char* __restrict__ wbt,
           char* __restrict__ Sb, char* __restrict__ Pb)
{
    const int t    = threadIdx.x;
    const int lane = t & 63;
    const int w    = t >> 6;        // wave -> col quarter
    const int q    = lane >> 4;     // k-subgroup 0..3
    const int p    = lane & 15;     // row (A) / col (B,D) within 16-tile
    const int m0   = blockIdx.x * 64;
    const int c0   = w * 64;        // combined output col base

    // A row pointers for the 4 row-tiles (clamped; static-indexed after unroll)
    const float* ar0;
    const float* ar1;
    const float* ar2;
    const float* ar3;
    {
        int r0 = m0 + 0 * 16 + p; if (r0 > NNODES - 1) r0 = NNODES - 1;
        int r1 = m0 + 1 * 16 + p; if (r1 > NNODES - 1) r1 = NNODES - 1;
        int r2 = m0 + 2 * 16 + p; if (r2 > NNODES - 1) r2 = NNODES - 1;
        int r3 = m0 + 3 * 16 + p; if (r3 > NNODES - 1) r3 = NNODES - 1;
        ar0 = feat + (size_t)r0 * FDIM;
        ar1 = feat + (size_t)r1 * FDIM;
        ar2 = feat + (size_t)r2 * FDIM;
        ar3 = feat + (size_t)r3 * FDIM;
    }

    f32x4 acc[4][4];   // [mi][n]
    #pragma unroll
    for (int mi = 0; mi < 4; ++mi)
        #pragma unroll
        for (int n = 0; n < 4; ++n) acc[mi][n] = (f32x4){0.f, 0.f, 0.f, 0.f};

    #pragma unroll
    for (int kt = 0; kt < 8; ++kt) {
        const int k0 = kt * 32 + q * 8;

        // B fragments: wave-private col panel, straight from L2
        bf16x8 bfr[4];
        #pragma unroll
        for (int n = 0; n < 4; ++n)
            bfr[n] = *(const bf16x8*)(wbt + (size_t)(c0 + n * 16 + p) * 512 + k0 * 2);

        #pragma unroll
        for (int mi = 0; mi < 4; ++mi) {
            const float* ap = (mi == 0) ? ar0 : (mi == 1) ? ar1 : (mi == 2) ? ar2 : ar3;
            const float4 lo = *(const float4*)(ap + k0);
            const float4 hi = *(const float4*)(ap + k0 + 4);
            bf16x8 af;
            af[0] = (__bf16)lo.x; af[1] = (__bf16)lo.y;
            af[2] = (__bf16)lo.z; af[3] = (__bf16)lo.w;
            af[4] = (__bf16)hi.x; af[5] = (__bf16)hi.y;
            af[6] = (__bf16)hi.z; af[7] = (__bf16)hi.w;
            #pragma unroll
            for (int n = 0; n < 4; ++n)
                acc[mi][n] = __builtin_amdgcn_mfma_f32_16x16x32_bf16(
                    af, bfr[n], acc[mi][n], 0, 0, 0);
        }
    }

    // epilogue: w<2 -> S cols, w>=2 -> P cols
    char* base   = (w < 2) ? Sb : Pb;
    const int cc = (w & 1) * 64;
    #pragma unroll
    for (int mi = 0; mi < 4; ++mi)
        #pragma unroll
        for (int jj = 0; jj < 4; ++jj) {
            const int row = m0 + mi * 16 + q * 4 + jj;
            if (row < NNODES) {
                #pragma unroll
                for (int n = 0; n < 4; ++n)
                    *(unsigned short*)(base + (size_t)row * 256 + (cc + n * 16 + p) * 2)
                        = f2bf(acc[mi][n][jj]);
            }
        }
}

// ---------------- kernel: gather2  out[b] = relu(S[nodes[b]] + mean_k P[neigh]) ------
__global__ __launch_bounds__(256, 4)
void gather2(const int* __restrict__ nodes, const int* __restrict__ neigh,
             const char* __restrict__ Sb, const char* __restrict__ Pb,
             float* __restrict__ out)
{
    const int lane = threadIdx.x & 63;
    const int b    = __builtin_amdgcn_readfirstlane(blockIdx.x * 4 + (threadIdx.x >> 6));

    const int nid = __builtin_amdgcn_readfirstlane(nodes[b]);
    const unsigned sv = *(const unsigned*)(Sb + (size_t)nid * 256 + lane * 4);

    const int* nb = neigh + (size_t)b * KN;
    float a0 = 0.f, a1 = 0.f;
    #pragma unroll
    for (int k = 0; k < KN; k += 8) {
        int id[8];
        #pragma unroll
        for (int j = 0; j < 8; ++j)
            id[j] = __builtin_amdgcn_readfirstlane(nb[k + j]);
        unsigned v[8];
        #pragma unroll
        for (int j = 0; j < 8; ++j)
            v[j] = *(const unsigned*)(Pb + (size_t)id[j] * 256 + lane * 4);
        #pragma unroll
        for (int j = 0; j < 8; ++j) {
            a0 += bflo(v[j]);
            a1 += bfhi(v[j]);
        }
    }

    const float inv = 1.0f / 32.0f;
    float o0 = bflo(sv) + a0 * inv;
    float o1 = bfhi(sv) + a1 * inv;
    o0 = o0 > 0.f ? o0 : 0.f;
    o1 = o1 > 0.f ? o1 : 0.f;
    ((float2*)out)[(size_t)b * 64 + lane] = make_float2(o0, o1);
}

// ================= fallback path (round-2): cat + gemm =================
#define CAT_BYTES ((size_t)BATCH * 1024)
#define WB_BYTES  ((size_t)512 * EDIM * 2)

__global__ void conv_w(const float* __restrict__ weight, char* __restrict__ wb)
{
    const int t  = blockIdx.x * 256 + threadIdx.x;
    const int c  = t & 127;
    const int g  = (t >> 7) & 15;
    const int kt = t >> 11;
    union { unsigned short u[8]; uint4 v; } p;
    #pragma unroll
    for (int j = 0; j < 8; ++j)
        p.u[j] = f2bf(weight[(size_t)(kt * 128 + g * 8 + j) * EDIM + c]);
    *(uint4*)(wb + (size_t)kt * 32768 + c * 256 + ((g * 16) ^ ((c & 7) << 4))) = p.v;
}

__global__ __launch_bounds__(256, 4)
void gather_agg(const int* __restrict__ nodes, const int* __restrict__ neigh,
                const float* __restrict__ feat, char* __restrict__ cat)
{
    const int lane = threadIdx.x & 63;
    const int row  = __builtin_amdgcn_readfirstlane(blockIdx.x * 4 + (threadIdx.x >> 6));
    const int s    = (row & 7) << 4;
    const int nid  = __builtin_amdgcn_readfirstlane(nodes[row]);
    float4 sf = ((const float4*)(feat + (size_t)nid * FDIM))[lane];
    const int* nb = neigh + (size_t)row * KN;
    float ax = 0.f, ay = 0.f, az = 0.f, aw = 0.f;
    #pragma unroll
    for (int k = 0; k < KN; k += 8) {
        int id[8];
        #pragma unroll
        for (int j = 0; j < 8; ++j) id[j] = __builtin_amdgcn_readfirstlane(nb[k + j]);
        float4 v[8];
        #pragma unroll
        for (int j = 0; j < 8; ++j) v[j] = ((const float4*)(feat + (size_t)id[j] * FDIM))[lane];
        #pragma unroll
        for (int j = 0; j < 8; ++j) { ax += v[j].x; ay += v[j].y; az += v[j].z; aw += v[j].w; }
    }
    char* rowp = cat + (size_t)row * 1024;
    {
        union { unsigned short u[4]; uint2 v; } p;
        p.u[0] = f2bf(sf.x); p.u[1] = f2bf(sf.y); p.u[2] = f2bf(sf.z); p.u[3] = f2bf(sf.w);
        *(uint2*)(rowp + ((lane * 8) ^ s)) = p.v;
    }
    {
        const float inv = 1.0f / 32.0f;
        union { unsigned short u[4]; uint2 v; } p;
        p.u[0] = f2bf(ax * inv); p.u[1] = f2bf(ay * inv);
        p.u[2] = f2bf(az * inv); p.u[3] = f2bf(aw * inv);
        *(uint2*)(rowp + ((512 + lane * 8) ^ s)) = p.v;
    }
}

__global__ __launch_bounds__(256, 2)
void gemm_out(const char* __restrict__ cat, const char* __restrict__ wb,
              float* __restrict__ out)
{
    __shared__ __align__(16) char lds_a[64 * 256];
    __shared__ __align__(16) char lds_b[128 * 256];
    const int t    = threadIdx.x;
    const int lane = t & 63;
    const int w    = t >> 6;
    const int m0   = blockIdx.x * 64;
    const int r0   = w * 16;
    const int q    = lane >> 4;
    const int p    = lane & 15;
    const int ps   = (p & 7) << 4;
    f32x4 acc[8];
    #pragma unroll
    for (int n = 0; n < 8; ++n) acc[n] = (f32x4){0.f, 0.f, 0.f, 0.f};
    for (int kt = 0; kt < 4; ++kt) {
        #pragma unroll
        for (int i = 0; i < 4; ++i) {
            const int g   = i * 256 + t;
            const int row = g >> 4;
            const int x   = (g & 15) * 16;
            __builtin_amdgcn_global_load_lds(
                (const void*)(cat + (size_t)(m0 + row) * 1024 + kt * 256 + x),
                (void*)(lds_a + g * 16), 16, 0, 0);
        }
        #pragma unroll
        for (int i = 0; i < 8; ++i) {
            const int g = i * 256 + t;
            __builtin_amdgcn_global_load_lds(
                (const void*)(wb + (size_t)kt * 32768 + g * 16),
                (void*)(lds_b + g * 16), 16, 0, 0);
        }
        __syncthreads();
        #pragma unroll
        for (int kk = 0; kk < 4; ++kk) {
            const int xo = (kk * 64 + q * 16);
            bf16x8 a = *(const bf16x8*)(lds_a + (r0 + p) * 256 + (xo ^ ps));
            #pragma unroll
            for (int n = 0; n < 8; ++n) {
                bf16x8 b = *(const bf16x8*)(lds_b + (n * 16 + p) * 256 + (xo ^ ps));
                acc[n] = __builtin_amdgcn_mfma_f32_16x16x32_bf16(a, b, acc[n], 0, 0, 0);
            }
        }
        __syncthreads();
    }
    #pragma unroll
    for (int n = 0; n < 8; ++n) {
        #pragma unroll
        for (int j = 0; j < 4; ++j) {
            const float v = acc[n][j];
            out[(size_t)(m0 + r0 + q * 4 + j) * EDIM + n * 16 + p] = v > 0.f ? v : 0.f;
        }
    }
}

extern "C" void kernel_launch(void* const* d_in, const int* in_sizes, int n_in,
                              void* d_out, int out_size, void* d_ws, size_t ws_size,
                              hipStream_t stream) {
    const int*   nodes  = (const int*)d_in[0];
    const int*   neigh  = (const int*)d_in[1];
    const float* feat   = (const float*)d_in[2];
    const float* weight = (const float*)d_in[3];
    float*       out    = (float*)d_out;

    if (ws_size >= NEW_WS) {
        char* Sb  = (char*)d_ws;
        char* Pb  = (char*)d_ws + SP_BYTES;
        char* wbt = (char*)d_ws + 2 * SP_BYTES;
        conv_w3<<<32, 256, 0, stream>>>(weight, wbt);
        proj6<<<(NNODES + 63) / 64, 256, 0, stream>>>(feat, wbt, Sb, Pb);
        gather2<<<BATCH / 4, 256, 0, stream>>>(nodes, neigh, Sb, Pb, out);
    } else {
        char* cat = (char*)d_ws;
        char* wb  = (char*)d_ws + CAT_BYTES;
        conv_w<<<32, 256, 0, stream>>>(weight, wb);
        gather_agg<<<BATCH / 4, 256, 0, stream>>>(nodes, neigh, feat, cat);
        gemm_out<<<BATCH / 64, 256, 0, stream>>>(cat, wb, out);
    }
}

// Round 9
// 67.825 us; speedup vs baseline: 1.6181x; 1.6181x over previous
//
#include <hip/hip_runtime.h>
#include <hip/hip_bf16.h>

#define BATCH  16384
#define FDIM   256
#define EDIM   128
#define KN     32
#define NNODES 100000

typedef __bf16 bf16x8 __attribute__((ext_vector_type(8)));
typedef float  f32x4  __attribute__((ext_vector_type(4)));

__device__ __forceinline__ unsigned short f2bf(float x) {
    return __builtin_bit_cast(unsigned short, (__bf16)x);
}
__device__ __forceinline__ float bflo(unsigned v) {
    return __builtin_bit_cast(float, v << 16);
}
__device__ __forceinline__ float bfhi(unsigned v) {
    return __builtin_bit_cast(float, v & 0xffff0000u);
}

// ---------- ws layout (new path) ----------
// Pb[NNODES][128] bf16        : neighbor head, all nodes
// Sbatch[BATCH][128] bf16     : self head, batch rows only
// wbtS, wbtP: per-head B^T bf16, 8 kt-chunks (BK=32) of [128 j][64 B],
//             16B granules XOR'd by (j&3)<<4 (pre-swizzled for linear global_load_lds)
#define PB_BYTES  ((size_t)NNODES * 256)
#define SBATCH_BYTES ((size_t)BATCH * 256)
#define WH_BYTES  ((size_t)8 * 128 * 64)
#define NEW_WS    (PB_BYTES + SBATCH_BYTES + 2 * WH_BYTES)

// ---------------- conv: W[512][128] f32 -> wbtS + wbtP ----------------
// head S: rows 0..255 of W; head P: rows 256..511.
__global__ void conv_w5(const float* __restrict__ weight,
                        char* __restrict__ wbtS, char* __restrict__ wbtP)
{
    const int gid  = blockIdx.x * 256 + threadIdx.x;  // 8192 granules
    const int head = gid >> 12;                       // 0=S, 1=P
    const int rem  = gid & 4095;
    const int kt   = rem >> 9;                        // 0..7
    const int j    = (rem >> 2) & 127;                // 0..127
    const int g    = rem & 3;                         // 0..3
    union { unsigned short u[8]; uint4 v; } p;
    #pragma unroll
    for (int e = 0; e < 8; ++e) {
        const int k = kt * 32 + g * 8 + e;
        p.u[e] = f2bf(weight[(size_t)(k + head * 256) * EDIM + j]);
    }
    char* dst = head ? wbtP : wbtS;
    *(uint4*)(dst + (size_t)kt * 8192 + j * 64 + ((g * 16) ^ ((j & 3) << 4))) = p.v;
}

// ---------------- projP: Pb = F @ W2  ----------------
// 512 thr / 8 waves; block = 128 rows x 128 cols; wave = 16 rows x 128 cols.
// A staged ONCE (dense row wave-loads -> cvt -> swizzled LDS, 64 KB).
// B staged per kt (8 KB) via global_load_lds from pre-swizzled wbtP.
__global__ __launch_bounds__(512, 2)
void projP(const float* __restrict__ feat, const char* __restrict__ wbt,
           char* __restrict__ Pb)
{
    __shared__ __align__(16) char ldsA[128 * 512];  // [128 r][512 B] bf16, swz (r&7)<<4
    __shared__ __align__(16) char ldsB[8192];       // [128 j][64 B] per kt, swz (j&3)<<4

    const int t    = threadIdx.x;
    const int lane = t & 63;
    const int w    = t >> 6;      // 0..7
    const int q    = lane >> 4;
    const int p    = lane & 15;
    const int m0   = blockIdx.x * 128;

    // ---- stage A once: wave w loads rows w*16 .. +16, one dense 1KB row per load
    #pragma unroll
    for (int i = 0; i < 16; ++i) {
        const int r   = w * 16 + i;
        int row = m0 + r; if (row > NNODES - 1) row = NNODES - 1;
        const float4 f = ((const float4*)(feat + (size_t)row * FDIM))[lane];
        union { unsigned short u[4]; uint2 v; } pk;
        pk.u[0] = f2bf(f.x); pk.u[1] = f2bf(f.y);
        pk.u[2] = f2bf(f.z); pk.u[3] = f2bf(f.w);
        *(uint2*)(ldsA + r * 512 + ((lane * 8) ^ ((r & 7) << 4))) = pk.v;
    }

    f32x4 acc[8];
    #pragma unroll
    for (int n = 0; n < 8; ++n) acc[n] = (f32x4){0.f, 0.f, 0.f, 0.f};

    const int ar = w * 16 + p;
    const int as = (p & 7) << 4;

    for (int kt = 0; kt < 8; ++kt) {
        // stage B chunk (8 KB): one 16B granule per thread, both sides linear
        __builtin_amdgcn_global_load_lds(
            (const void*)(wbt + (size_t)kt * 8192 + t * 16),
            (void*)(ldsB + t * 16), 16, 0, 0);
        __syncthreads();   // drains vmcnt+lgkmcnt (covers A-stage on kt=0)

        const bf16x8 a = *(const bf16x8*)(ldsA + ar * 512
                             + ((kt * 64 + q * 16) ^ as));
        #pragma unroll
        for (int n = 0; n < 8; ++n) {
            const int j = n * 16 + p;
            const bf16x8 b = *(const bf16x8*)(ldsB + j * 64
                                 + ((q * 16) ^ ((j & 3) << 4)));
            acc[n] = __builtin_amdgcn_mfma_f32_16x16x32_bf16(a, b, acc[n], 0, 0, 0);
        }
        __syncthreads();
    }

    #pragma unroll
    for (int n = 0; n < 8; ++n)
        #pragma unroll
        for (int jj = 0; jj < 4; ++jj) {
            const int row = m0 + w * 16 + q * 4 + jj;
            if (row < NNODES)
                *(unsigned short*)(Pb + (size_t)row * 256 + (n * 16 + p) * 2)
                    = f2bf(acc[n][jj]);
        }
}

// ---------------- selfgemm: Sbatch = F[nodes] @ W1 ----------------
// 256 thr / 4 waves; block = 64 batch rows x 128 cols.
// A gathered directly into LDS via per-lane-source global_load_lds (f32, 64 KB),
// 16B granules source-preswizzled by (r&7)<<4; B staged per kt (8 KB).
__global__ __launch_bounds__(256, 2)
void selfgemm(const int* __restrict__ nodes, const float* __restrict__ feat,
              const char* __restrict__ wbt, char* __restrict__ Sbatch)
{
    __shared__ __align__(16) char ldsA[64 * 1024];  // [64 r][1024 B] f32, swz (r&7)<<4
    __shared__ __align__(16) char ldsB[8192];       // [128 j][64 B] per kt

    const int t    = threadIdx.x;
    const int lane = t & 63;
    const int w    = t >> 6;      // 0..3
    const int q    = lane >> 4;
    const int p    = lane & 15;
    const int m0   = blockIdx.x * 64;

    // ---- gather-stage A once: 4096 granules, 16 per thread
    #pragma unroll
    for (int i = 0; i < 16; ++i) {
        const int g = i * 256 + t;
        const int r = g >> 6;              // 0..63
        const int x = (g & 63) * 16;       // byte within 1KB row
        const int nid = nodes[m0 + r];
        __builtin_amdgcn_global_load_lds(
            (const void*)((const char*)feat + (size_t)nid * 1024
                          + (x ^ ((r & 7) << 4))),
            (void*)(ldsA + (size_t)r * 1024 + x), 16, 0, 0);
    }

    f32x4 acc[8];
    #pragma unroll
    for (int n = 0; n < 8; ++n) acc[n] = (f32x4){0.f, 0.f, 0.f, 0.f};

    const int ar = w * 16 + p;
    const int as = (p & 7) << 4;

    for (int kt = 0; kt < 8; ++kt) {
        #pragma unroll
        for (int i = 0; i < 2; ++i) {
            const int g = i * 256 + t;
            __builtin_amdgcn_global_load_lds(
                (const void*)(wbt + (size_t)kt * 8192 + g * 16),
                (void*)(ldsB + g * 16), 16, 0, 0);
        }
        __syncthreads();

        const f32x4 lo = *(const f32x4*)(ldsA + (size_t)ar * 1024
                             + ((kt * 128 + q * 32) ^ as));
        const f32x4 hi = *(const f32x4*)(ldsA + (size_t)ar * 1024
                             + ((kt * 128 + q * 32 + 16) ^ as));
        bf16x8 a;
        a[0] = (__bf16)lo[0]; a[1] = (__bf16)lo[1];
        a[2] = (__bf16)lo[2]; a[3] = (__bf16)lo[3];
        a[4] = (__bf16)hi[0]; a[5] = (__bf16)hi[1];
        a[6] = (__bf16)hi[2]; a[7] = (__bf16)hi[3];

        #pragma unroll
        for (int n = 0; n < 8; ++n) {
            const int j = n * 16 + p;
            const bf16x8 b = *(const bf16x8*)(ldsB + j * 64
                                 + ((q * 16) ^ ((j & 3) << 4)));
            acc[n] = __builtin_amdgcn_mfma_f32_16x16x32_bf16(a, b, acc[n], 0, 0, 0);
        }
        __syncthreads();
    }

    #pragma unroll
    for (int n = 0; n < 8; ++n)
        #pragma unroll
        for (int jj = 0; jj < 4; ++jj) {
            const int row = m0 + w * 16 + q * 4 + jj;   // < BATCH always
            *(unsigned short*)(Sbatch + (size_t)row * 256 + (n * 16 + p) * 2)
                = f2bf(acc[n][jj]);
        }
}

// ---------------- gather3: out[b] = relu(Sbatch[b] + mean_k Pb[neigh]) ------
__global__ __launch_bounds__(256, 4)
void gather3(const int* __restrict__ neigh, const char* __restrict__ Sbatch,
             const char* __restrict__ Pb, float* __restrict__ out)
{
    const int lane = threadIdx.x & 63;
    const int b    = __builtin_amdgcn_readfirstlane(blockIdx.x * 4 + (threadIdx.x >> 6));

    const unsigned sv = *(const unsigned*)(Sbatch + (size_t)b * 256 + lane * 4);

    const int* nb = neigh + (size_t)b * KN;
    float a0 = 0.f, a1 = 0.f;
    #pragma unroll
    for (int k = 0; k < KN; k += 8) {
        int id[8];
        #pragma unroll
        for (int j = 0; j < 8; ++j)
            id[j] = __builtin_amdgcn_readfirstlane(nb[k + j]);
        unsigned v[8];
        #pragma unroll
        for (int j = 0; j < 8; ++j)
            v[j] = *(const unsigned*)(Pb + (size_t)id[j] * 256 + lane * 4);
        #pragma unroll
        for (int j = 0; j < 8; ++j) {
            a0 += bflo(v[j]);
            a1 += bfhi(v[j]);
        }
    }

    const float inv = 1.0f / 32.0f;
    float o0 = bflo(sv) + a0 * inv;
    float o1 = bfhi(sv) + a1 * inv;
    o0 = o0 > 0.f ? o0 : 0.f;
    o1 = o1 > 0.f ? o1 : 0.f;
    ((float2*)out)[(size_t)b * 64 + lane] = make_float2(o0, o1);
}

// ================= fallback path (round-2): cat + gemm =================
#define CAT_BYTES ((size_t)BATCH * 1024)
#define WB_BYTES  ((size_t)512 * EDIM * 2)

__global__ void conv_w(const float* __restrict__ weight, char* __restrict__ wb)
{
    const int t  = blockIdx.x * 256 + threadIdx.x;
    const int c  = t & 127;
    const int g  = (t >> 7) & 15;
    const int kt = t >> 11;
    union { unsigned short u[8]; uint4 v; } p;
    #pragma unroll
    for (int j = 0; j < 8; ++j)
        p.u[j] = f2bf(weight[(size_t)(kt * 128 + g * 8 + j) * EDIM + c]);
    *(uint4*)(wb + (size_t)kt * 32768 + c * 256 + ((g * 16) ^ ((c & 7) << 4))) = p.v;
}

__global__ __launch_bounds__(256, 4)
void gather_agg(const int* __restrict__ nodes, const int* __restrict__ neigh,
                const float* __restrict__ feat, char* __restrict__ cat)
{
    const int lane = threadIdx.x & 63;
    const int row  = __builtin_amdgcn_readfirstlane(blockIdx.x * 4 + (threadIdx.x >> 6));
    const int s    = (row & 7) << 4;
    const int nid  = __builtin_amdgcn_readfirstlane(nodes[row]);
    float4 sf = ((const float4*)(feat + (size_t)nid * FDIM))[lane];
    const int* nb = neigh + (size_t)row * KN;
    float ax = 0.f, ay = 0.f, az = 0.f, aw = 0.f;
    #pragma unroll
    for (int k = 0; k < KN; k += 8) {
        int id[8];
        #pragma unroll
        for (int j = 0; j < 8; ++j) id[j] = __builtin_amdgcn_readfirstlane(nb[k + j]);
        float4 v[8];
        #pragma unroll
        for (int j = 0; j < 8; ++j) v[j] = ((const float4*)(feat + (size_t)id[j] * FDIM))[lane];
        #pragma unroll
        for (int j = 0; j < 8; ++j) { ax += v[j].x; ay += v[j].y; az += v[j].z; aw += v[j].w; }
    }
    char* rowp = cat + (size_t)row * 1024;
    {
        union { unsigned short u[4]; uint2 v; } p;
        p.u[0] = f2bf(sf.x); p.u[1] = f2bf(sf.y); p.u[2] = f2bf(sf.z); p.u[3] = f2bf(sf.w);
        *(uint2*)(rowp + ((lane * 8) ^ s)) = p.v;
    }
    {
        const float inv = 1.0f / 32.0f;
        union { unsigned short u[4]; uint2 v; } p;
        p.u[0] = f2bf(ax * inv); p.u[1] = f2bf(ay * inv);
        p.u[2] = f2bf(az * inv); p.u[3] = f2bf(aw * inv);
        *(uint2*)(rowp + ((512 + lane * 8) ^ s)) = p.v;
    }
}

__global__ __launch_bounds__(256, 2)
void gemm_out(const char* __restrict__ cat, const char* __restrict__ wb,
              float* __restrict__ out)
{
    __shared__ __align__(16) char lds_a[64 * 256];
    __shared__ __align__(16) char lds_b[128 * 256];
    const int t    = threadIdx.x;
    const int lane = t & 63;
    const int w    = t >> 6;
    const int m0   = blockIdx.x * 64;
    const int r0   = w * 16;
    const int q    = lane >> 4;
    const int p    = lane & 15;
    const int ps   = (p & 7) << 4;
    f32x4 acc[8];
    #pragma unroll
    for (int n = 0; n < 8; ++n) acc[n] = (f32x4){0.f, 0.f, 0.f, 0.f};
    for (int kt = 0; kt < 4; ++kt) {
        #pragma unroll
        for (int i = 0; i < 4; ++i) {
            const int g   = i * 256 + t;
            const int row = g >> 4;
            const int x   = (g & 15) * 16;
            __builtin_amdgcn_global_load_lds(
                (const void*)(cat + (size_t)(m0 + row) * 1024 + kt * 256 + x),
                (void*)(lds_a + g * 16), 16, 0, 0);
        }
        #pragma unroll
        for (int i = 0; i < 8; ++i) {
            const int g = i * 256 + t;
            __builtin_amdgcn_global_load_lds(
                (const void*)(wb + (size_t)kt * 32768 + g * 16),
                (void*)(lds_b + g * 16), 16, 0, 0);
        }
        __syncthreads();
        #pragma unroll
        for (int kk = 0; kk < 4; ++kk) {
            const int xo = (kk * 64 + q * 16);
            bf16x8 a = *(const bf16x8*)(lds_a + (r0 + p) * 256 + (xo ^ ps));
            #pragma unroll
            for (int n = 0; n < 8; ++n) {
                bf16x8 b = *(const bf16x8*)(lds_b + (n * 16 + p) * 256 + (xo ^ ps));
                acc[n] = __builtin_amdgcn_mfma_f32_16x16x32_bf16(a, b, acc[n], 0, 0, 0);
            }
        }
        __syncthreads();
    }
    #pragma unroll
    for (int n = 0; n < 8; ++n) {
        #pragma unroll
        for (int j = 0; j < 4; ++j) {
            const float v = acc[n][j];
            out[(size_t)(m0 + r0 + q * 4 + j) * EDIM + n * 16 + p] = v > 0.f ? v : 0.f;
        }
    }
}

extern "C" void kernel_launch(void* const* d_in, const int* in_sizes, int n_in,
                              void* d_out, int out_size, void* d_ws, size_t ws_size,
                              hipStream_t stream) {
    const int*   nodes  = (const int*)d_in[0];
    const int*   neigh  = (const int*)d_in[1];
    const float* feat   = (const float*)d_in[2];
    const float* weight = (const float*)d_in[3];
    float*       out    = (float*)d_out;

    if (ws_size >= NEW_WS) {
        char* Pb     = (char*)d_ws;
        char* Sbatch = (char*)d_ws + PB_BYTES;
        char* wbtS   = (char*)d_ws + PB_BYTES + SBATCH_BYTES;
        char* wbtP   = wbtS + WH_BYTES;
        conv_w5<<<32, 256, 0, stream>>>(weight, wbtS, wbtP);
        selfgemm<<<BATCH / 64, 256, 0, stream>>>(nodes, feat, wbtS, Sbatch);
        projP<<<(NNODES + 127) / 128, 512, 0, stream>>>(feat, wbtP, Pb);
        gather3<<<BATCH / 4, 256, 0, stream>>>(neigh, Sbatch, Pb, out);
    } else {
        char* cat = (char*)d_ws;
        char* wb  = (char*)d_ws + CAT_BYTES;
        conv_w<<<32, 256, 0, stream>>>(weight, wb);
        gather_agg<<<BATCH / 4, 256, 0, stream>>>(nodes, neigh, feat, cat);
        gemm_out<<<BATCH / 64, 256, 0, stream>>>(cat, wb, out);
    }
}

// Round 10
// 65.136 us; speedup vs baseline: 1.6849x; 1.0413x over previous
//
#include <hip/hip_runtime.h>
#include <hip/hip_bf16.h>

#define BATCH  16384
#define FDIM   256
#define EDIM   128
#define KN     32
#define NNODES 100000

typedef __bf16 bf16x8 __attribute__((ext_vector_type(8)));
typedef float  f32x4  __attribute__((ext_vector_type(4)));

__device__ __forceinline__ unsigned short f2bf(float x) {
    return __builtin_bit_cast(unsigned short, (__bf16)x);
}
__device__ __forceinline__ float bflo(unsigned v) {
    return __builtin_bit_cast(float, v << 16);
}
__device__ __forceinline__ float bfhi(unsigned v) {
    return __builtin_bit_cast(float, v & 0xffff0000u);
}

// ---------- ws layout (new path) ----------
// Pb[NNODES][128] bf16      : neighbor head, all nodes
// Sbatch[BATCH][128] bf16   : self head, batch rows only
// wbtS, wbtP: per-head B^T bf16, [2 halves][128 j][256 B] (k-half = 128 k),
//             16B granules XOR'd by (j&7)<<4 (pre-swizzled for linear global_load_lds)
#define PB_BYTES     ((size_t)NNODES * 256)
#define SBATCH_BYTES ((size_t)BATCH * 256)
#define WH_BYTES     ((size_t)2 * 128 * 256)     // 64 KB per head
#define NEW_WS       (PB_BYTES + SBATCH_BYTES + 2 * WH_BYTES)

// ---------------- conv: W[512][128] f32 -> wbtS + wbtP ----------------
// head S: W rows 0..255 ; head P: W rows 256..511
__global__ void conv_w6(const float* __restrict__ weight,
                        char* __restrict__ wbtS, char* __restrict__ wbtP)
{
    const int gid  = blockIdx.x * 256 + threadIdx.x;  // 8192 granules
    const int head = gid >> 12;                       // 0=S, 1=P
    const int H    = (gid >> 11) & 1;                 // k-half
    const int j    = (gid >> 4) & 127;                // col
    const int g    = gid & 15;                        // 16B granule in 256B row
    union { unsigned short u[8]; uint4 v; } p;
    #pragma unroll
    for (int e = 0; e < 8; ++e) {
        const int k = H * 128 + g * 8 + e;
        p.u[e] = f2bf(weight[(size_t)(k + head * 256) * EDIM + j]);
    }
    char* dst = head ? wbtP : wbtS;
    *(uint4*)(dst + (size_t)H * 32768 + j * 256 + ((g * 16) ^ ((j & 7) << 4))) = p.v;
}

// ---------------- proj7: Pb = F @ W2 ----------------
// 256 thr / 4 waves; block = 64 rows x 128 cols. 4 barriers TOTAL.
// A staged once (full K=256 bf16, 32 KB) via dense batched row loads;
// B staged in two 32 KB halves via linear global_load_lds.
__global__ __launch_bounds__(256, 2)
void proj7(const float* __restrict__ feat, const char* __restrict__ wbt,
           char* __restrict__ Pb)
{
    __shared__ __align__(16) char ldsA[64 * 512];   // [64 r][512 B] bf16, swz (r&7)<<4
    __shared__ __align__(16) char ldsB[32768];      // [128 j][256 B] per half, swz (j&7)<<4

    const int t    = threadIdx.x;
    const int lane = t & 63;
    const int w    = t >> 6;
    const int q    = lane >> 4;
    const int p    = lane & 15;
    const int m0   = blockIdx.x * 64;

    // issue B half-0 stage early
    #pragma unroll
    for (int i = 0; i < 8; ++i) {
        const int g = i * 256 + t;
        __builtin_amdgcn_global_load_lds((const void*)(wbt + g * 16),
                                         (void*)(ldsB + g * 16), 16, 0, 0);
    }

    // A-stage: wave w rows w*16..+15, two 8-deep batches (gather_agg pattern)
    #pragma unroll
    for (int batch = 0; batch < 2; ++batch) {
        float4 v[8];
        #pragma unroll
        for (int jj = 0; jj < 8; ++jj) {
            int row = m0 + w * 16 + batch * 8 + jj;
            if (row > NNODES - 1) row = NNODES - 1;
            v[jj] = ((const float4*)(feat + (size_t)row * FDIM))[lane];
        }
        #pragma unroll
        for (int jj = 0; jj < 8; ++jj) {
            const int r = w * 16 + batch * 8 + jj;
            union { unsigned short u[4]; uint2 x; } pk;
            pk.u[0] = f2bf(v[jj].x); pk.u[1] = f2bf(v[jj].y);
            pk.u[2] = f2bf(v[jj].z); pk.u[3] = f2bf(v[jj].w);
            *(uint2*)(ldsA + r * 512 + ((lane * 8) ^ ((r & 7) << 4))) = pk.x;
        }
    }

    f32x4 acc[8];
    #pragma unroll
    for (int n = 0; n < 8; ++n) acc[n] = (f32x4){0.f, 0.f, 0.f, 0.f};

#define PCOMPUTE(H)                                                          \
    do {                                                                     \
        _Pragma("unroll")                                                    \
        for (int kt = 0; kt < 4; ++kt) {                                     \
            const int ar = w * 16 + p;                                       \
            const bf16x8 a = *(const bf16x8*)(ldsA + ar * 512 +              \
                (((H) * 256 + kt * 64 + q * 16) ^ ((ar & 7) << 4)));         \
            _Pragma("unroll")                                                \
            for (int n = 0; n < 8; ++n) {                                    \
                const int j = n * 16 + p;                                    \
                const bf16x8 b = *(const bf16x8*)(ldsB + j * 256 +           \
                    ((kt * 64 + q * 16) ^ ((j & 7) << 4)));                  \
                acc[n] = __builtin_amdgcn_mfma_f32_16x16x32_bf16(            \
                    a, b, acc[n], 0, 0, 0);                                  \
            }                                                                \
        }                                                                    \
    } while (0)

    __syncthreads();           // drains A v-loads/ds_writes + B0 gloads
    PCOMPUTE(0);
    __syncthreads();           // everyone done reading B0
    #pragma unroll
    for (int i = 0; i < 8; ++i) {
        const int g = i * 256 + t;
        __builtin_amdgcn_global_load_lds((const void*)(wbt + 32768 + g * 16),
                                         (void*)(ldsB + g * 16), 16, 0, 0);
    }
    __syncthreads();           // B1 staged
    PCOMPUTE(1);
#undef PCOMPUTE

    #pragma unroll
    for (int n = 0; n < 8; ++n)
        #pragma unroll
        for (int jj = 0; jj < 4; ++jj) {
            const int row = m0 + w * 16 + q * 4 + jj;
            if (row < NNODES)
                *(unsigned short*)(Pb + (size_t)row * 256 + (n * 16 + p) * 2)
                    = f2bf(acc[n][jj]);
        }
}

// ---------------- selfg2: Sbatch = F[nodes] @ W1 ----------------
// 256 thr / 4 waves; block = 64 batch rows x 128 cols; grid 256 = 1 block/CU.
// A gathered once into LDS (f32, 64 KB) via per-lane-source global_load_lds.
__global__ __launch_bounds__(256, 1)
void selfg2(const int* __restrict__ nodes, const float* __restrict__ feat,
            const char* __restrict__ wbt, char* __restrict__ Sbatch)
{
    __shared__ __align__(16) char ldsA[64 * 1024];  // [64 r][1024 B] f32, swz (r&7)<<4
    __shared__ __align__(16) char ldsB[32768];      // [128 j][256 B] per half

    const int t    = threadIdx.x;
    const int lane = t & 63;
    const int w    = t >> 6;
    const int q    = lane >> 4;
    const int p    = lane & 15;
    const int m0   = blockIdx.x * 64;

    // B half-0 first
    #pragma unroll
    for (int i = 0; i < 8; ++i) {
        const int g = i * 256 + t;
        __builtin_amdgcn_global_load_lds((const void*)(wbt + g * 16),
                                         (void*)(ldsB + g * 16), 16, 0, 0);
    }
    // A gather-stage: 16 granules/thread, dest linear, source pre-swizzled
    #pragma unroll
    for (int i = 0; i < 16; ++i) {
        const int g = i * 256 + t;
        const int r = g >> 6;
        const int x = (g & 63) * 16;
        const int nid = nodes[m0 + r];
        __builtin_amdgcn_global_load_lds(
            (const void*)((const char*)feat + (size_t)nid * 1024
                          + (x ^ ((r & 7) << 4))),
            (void*)(ldsA + (size_t)r * 1024 + x), 16, 0, 0);
    }

    f32x4 acc[8];
    #pragma unroll
    for (int n = 0; n < 8; ++n) acc[n] = (f32x4){0.f, 0.f, 0.f, 0.f};

#define SCOMPUTE(H)                                                          \
    do {                                                                     \
        _Pragma("unroll")                                                    \
        for (int kt = 0; kt < 4; ++kt) {                                     \
            const int ar = w * 16 + p;                                       \
            const int sw = (ar & 7) << 4;                                    \
            const f32x4 lo = *(const f32x4*)(ldsA + (size_t)ar * 1024 +      \
                (((H) * 512 + kt * 128 + q * 32) ^ sw));                     \
            const f32x4 hi = *(const f32x4*)(ldsA + (size_t)ar * 1024 +      \
                (((H) * 512 + kt * 128 + q * 32 + 16) ^ sw));                \
            bf16x8 a;                                                        \
            a[0] = (__bf16)lo[0]; a[1] = (__bf16)lo[1];                      \
            a[2] = (__bf16)lo[2]; a[3] = (__bf16)lo[3];                      \
            a[4] = (__bf16)hi[0]; a[5] = (__bf16)hi[1];                      \
            a[6] = (__bf16)hi[2]; a[7] = (__bf16)hi[3];                      \
            _Pragma("unroll")                                                \
            for (int n = 0; n < 8; ++n) {                                    \
                const int j = n * 16 + p;                                    \
                const bf16x8 b = *(const bf16x8*)(ldsB + j * 256 +           \
                    ((kt * 64 + q * 16) ^ ((j & 7) << 4)));                  \
                acc[n] = __builtin_amdgcn_mfma_f32_16x16x32_bf16(            \
                    a, b, acc[n], 0, 0, 0);                                  \
            }                                                                \
        }                                                                    \
    } while (0)

    __syncthreads();
    SCOMPUTE(0);
    __syncthreads();
    #pragma unroll
    for (int i = 0; i < 8; ++i) {
        const int g = i * 256 + t;
        __builtin_amdgcn_global_load_lds((const void*)(wbt + 32768 + g * 16),
                                         (void*)(ldsB + g * 16), 16, 0, 0);
    }
    __syncthreads();
    SCOMPUTE(1);
#undef SCOMPUTE

    #pragma unroll
    for (int n = 0; n < 8; ++n)
        #pragma unroll
        for (int jj = 0; jj < 4; ++jj) {
            const int row = m0 + w * 16 + q * 4 + jj;   // < BATCH always
            *(unsigned short*)(Sbatch + (size_t)row * 256 + (n * 16 + p) * 2)
                = f2bf(acc[n][jj]);
        }
}

// ---------------- gather3: out[b] = relu(Sbatch[b] + mean_k Pb[neigh]) ------
__global__ __launch_bounds__(256, 4)
void gather3(const int* __restrict__ neigh, const char* __restrict__ Sbatch,
             const char* __restrict__ Pb, float* __restrict__ out)
{
    const int lane = threadIdx.x & 63;
    const int b    = __builtin_amdgcn_readfirstlane(blockIdx.x * 4 + (threadIdx.x >> 6));

    const unsigned sv = *(const unsigned*)(Sbatch + (size_t)b * 256 + lane * 4);

    const int* nb = neigh + (size_t)b * KN;
    float a0 = 0.f, a1 = 0.f;
    #pragma unroll
    for (int k = 0; k < KN; k += 8) {
        int id[8];
        #pragma unroll
        for (int j = 0; j < 8; ++j)
            id[j] = __builtin_amdgcn_readfirstlane(nb[k + j]);
        unsigned v[8];
        #pragma unroll
        for (int j = 0; j < 8; ++j)
            v[j] = *(const unsigned*)(Pb + (size_t)id[j] * 256 + lane * 4);
        #pragma unroll
        for (int j = 0; j < 8; ++j) {
            a0 += bflo(v[j]);
            a1 += bfhi(v[j]);
        }
    }

    const float inv = 1.0f / 32.0f;
    float o0 = bflo(sv) + a0 * inv;
    float o1 = bfhi(sv) + a1 * inv;
    o0 = o0 > 0.f ? o0 : 0.f;
    o1 = o1 > 0.f ? o1 : 0.f;
    ((float2*)out)[(size_t)b * 64 + lane] = make_float2(o0, o1);
}

// ================= fallback path (round-2): cat + gemm =================
#define CAT_BYTES ((size_t)BATCH * 1024)
#define WB_BYTES  ((size_t)512 * EDIM * 2)

__global__ void conv_w(const float* __restrict__ weight, char* __restrict__ wb)
{
    const int t  = blockIdx.x * 256 + threadIdx.x;
    const int c  = t & 127;
    const int g  = (t >> 7) & 15;
    const int kt = t >> 11;
    union { unsigned short u[8]; uint4 v; } p;
    #pragma unroll
    for (int j = 0; j < 8; ++j)
        p.u[j] = f2bf(weight[(size_t)(kt * 128 + g * 8 + j) * EDIM + c]);
    *(uint4*)(wb + (size_t)kt * 32768 + c * 256 + ((g * 16) ^ ((c & 7) << 4))) = p.v;
}

__global__ __launch_bounds__(256, 4)
void gather_agg(const int* __restrict__ nodes, const int* __restrict__ neigh,
                const float* __restrict__ feat, char* __restrict__ cat)
{
    const int lane = threadIdx.x & 63;
    const int row  = __builtin_amdgcn_readfirstlane(blockIdx.x * 4 + (threadIdx.x >> 6));
    const int s    = (row & 7) << 4;
    const int nid  = __builtin_amdgcn_readfirstlane(nodes[row]);
    float4 sf = ((const float4*)(feat + (size_t)nid * FDIM))[lane];
    const int* nb = neigh + (size_t)row * KN;
    float ax = 0.f, ay = 0.f, az = 0.f, aw = 0.f;
    #pragma unroll
    for (int k = 0; k < KN; k += 8) {
        int id[8];
        #pragma unroll
        for (int j = 0; j < 8; ++j) id[j] = __builtin_amdgcn_readfirstlane(nb[k + j]);
        float4 v[8];
        #pragma unroll
        for (int j = 0; j < 8; ++j) v[j] = ((const float4*)(feat + (size_t)id[j] * FDIM))[lane];
        #pragma unroll
        for (int j = 0; j < 8; ++j) { ax += v[j].x; ay += v[j].y; az += v[j].z; aw += v[j].w; }
    }
    char* rowp = cat + (size_t)row * 1024;
    {
        union { unsigned short u[4]; uint2 v; } p;
        p.u[0] = f2bf(sf.x); p.u[1] = f2bf(sf.y); p.u[2] = f2bf(sf.z); p.u[3] = f2bf(sf.w);
        *(uint2*)(rowp + ((lane * 8) ^ s)) = p.v;
    }
    {
        const float inv = 1.0f / 32.0f;
        union { unsigned short u[4]; uint2 v; } p;
        p.u[0] = f2bf(ax * inv); p.u[1] = f2bf(ay * inv);
        p.u[2] = f2bf(az * inv); p.u[3] = f2bf(aw * inv);
        *(uint2*)(rowp + ((512 + lane * 8) ^ s)) = p.v;
    }
}

__global__ __launch_bounds__(256, 2)
void gemm_out(const char* __restrict__ cat, const char* __restrict__ wb,
              float* __restrict__ out)
{
    __shared__ __align__(16) char lds_a[64 * 256];
    __shared__ __align__(16) char lds_b[128 * 256];
    const int t    = threadIdx.x;
    const int lane = t & 63;
    const int w    = t >> 6;
    const int m0   = blockIdx.x * 64;
    const int r0   = w * 16;
    const int q    = lane >> 4;
    const int p    = lane & 15;
    const int ps   = (p & 7) << 4;
    f32x4 acc[8];
    #pragma unroll
    for (int n = 0; n < 8; ++n) acc[n] = (f32x4){0.f, 0.f, 0.f, 0.f};
    for (int kt = 0; kt < 4; ++kt) {
        #pragma unroll
        for (int i = 0; i < 4; ++i) {
            const int g   = i * 256 + t;
            const int row = g >> 4;
            const int x   = (g & 15) * 16;
            __builtin_amdgcn_global_load_lds(
                (const void*)(cat + (size_t)(m0 + row) * 1024 + kt * 256 + x),
                (void*)(lds_a + g * 16), 16, 0, 0);
        }
        #pragma unroll
        for (int i = 0; i < 8; ++i) {
            const int g = i * 256 + t;
            __builtin_amdgcn_global_load_lds(
                (const void*)(wb + (size_t)kt * 32768 + g * 16),
                (void*)(lds_b + g * 16), 16, 0, 0);
        }
        __syncthreads();
        #pragma unroll
        for (int kk = 0; kk < 4; ++kk) {
            const int xo = (kk * 64 + q * 16);
            bf16x8 a = *(const bf16x8*)(lds_a + (r0 + p) * 256 + (xo ^ ps));
            #pragma unroll
            for (int n = 0; n < 8; ++n) {
                bf16x8 b = *(const bf16x8*)(lds_b + (n * 16 + p) * 256 + (xo ^ ps));
                acc[n] = __builtin_amdgcn_mfma_f32_16x16x32_bf16(a, b, acc[n], 0, 0, 0);
            }
        }
        __syncthreads();
    }
    #pragma unroll
    for (int n = 0; n < 8; ++n) {
        #pragma unroll
        for (int j = 0; j < 4; ++j) {
            const float v = acc[n][j];
            out[(size_t)(m0 + r0 + q * 4 + j) * EDIM + n * 16 + p] = v > 0.f ? v : 0.f;
        }
    }
}

extern "C" void kernel_launch(void* const* d_in, const int* in_sizes, int n_in,
                              void* d_out, int out_size, void* d_ws, size_t ws_size,
                              hipStream_t stream) {
    const int*   nodes  = (const int*)d_in[0];
    const int*   neigh  = (const int*)d_in[1];
    const float* feat   = (const float*)d_in[2];
    const float* weight = (const float*)d_in[3];
    float*       out    = (float*)d_out;

    if (ws_size >= NEW_WS) {
        char* Pb     = (char*)d_ws;
        char* Sbatch = (char*)d_ws + PB_BYTES;
        char* wbtS   = (char*)d_ws + PB_BYTES + SBATCH_BYTES;
        char* wbtP   = wbtS + WH_BYTES;
        conv_w6<<<32, 256, 0, stream>>>(weight, wbtS, wbtP);
        proj7<<<(NNODES + 63) / 64, 256, 0, stream>>>(feat, wbtP, Pb);
        selfg2<<<BATCH / 64, 256, 0, stream>>>(nodes, feat, wbtS, Sbatch);
        gather3<<<BATCH / 4, 256, 0, stream>>>(neigh, Sbatch, Pb, out);
    } else {
        char* cat = (char*)d_ws;
        char* wb  = (char*)d_ws + CAT_BYTES;
        conv_w<<<32, 256, 0, stream>>>(weight, wb);
        gather_agg<<<BATCH / 4, 256, 0, stream>>>(nodes, neigh, feat, cat);
        gemm_out<<<BATCH / 64, 256, 0, stream>>>(cat, wb, out);
    }
}